// Round 13
// baseline (1606.251 us; speedup 1.0000x reference)
//
#include <hip/hip_runtime.h>
#include <math.h>

#define N_NODES  100000
#define N_EDGES  3200000
#define N_GRAPHS 256
#define F        64

// bucketed grouping params (no within-bucket sort)
#define BSHIFT   7
#define BNODES   128                    // nodes per bucket
#define NBKT     782                    // ceil(N_NODES / BNODES)
#define NCH      1024                   // edge chunks
#define CHUNK    3125                   // edges per chunk (NCH*CHUNK == N_EDGES)

// s1 quantization: 8192 levels over [-8, 8); step = 1/512
#define QLEV     8192
#define QSCALE   512.0f
#define QINV     (1.0f / 512.0f)

typedef _Float16 f16;
typedef __attribute__((ext_vector_type(4))) _Float16 f16x4;
typedef __attribute__((ext_vector_type(8))) _Float16 f16x8;

__device__ __forceinline__ float gelu_f(float x) {
    float x3 = x * x * x;
    float inner = 0.7978845608028654f * (x + 0.044715f * x3);
    return 0.5f * x * (1.0f + tanhf(inner));
}

// fast gelu: 0.5x(1+tanh(u)) = x*(1-rcp(exp2(2u*log2e)+1)); ~1ulp exp2/rcp
__device__ __forceinline__ float gelu_fast(float x) {
    const float c1 = 2.3022082232f;     // 2*log2(e)*0.7978845608
    const float c2 = 0.1029432407f;     // c1*0.044715
    float x2 = x * x;
    float t  = x * fmaf(c2, x2, c1);
    float E  = __builtin_amdgcn_exp2f(t);
    float r  = __builtin_amdgcn_rcpf(E + 1.0f);
    return fmaf(-x, r, x);
}

__device__ __forceinline__ float f16bits_to_f(unsigned short u) {
    f16 h = *(f16*)&u;
    return (float)h;
}

// ---- gelu lookup table: table[q][f] = fp16(gelu(s_q*W1_f + b1_f)) ---------
__global__ void __launch_bounds__(256) k_table(const float* __restrict__ W1,
                                               const float* __restrict__ b1,
                                               f16* __restrict__ table) {
    int i = blockIdx.x * 256 + threadIdx.x;      // QLEV*16 items
    int q  = i >> 4;
    int f4 = (i & 15) << 2;
    float s = (float)q * QINV - 8.0f;
    const float4 w  = *(const float4*)(W1 + f4);
    const float4 bb = *(const float4*)(b1 + f4);
    f16x4 o;
    o.x = (f16)gelu_fast(fmaf(s, w.x, bb.x));
    o.y = (f16)gelu_fast(fmaf(s, w.y, bb.y));
    o.z = (f16)gelu_fast(fmaf(s, w.z, bb.z));
    o.w = (f16)gelu_fast(fmaf(s, w.w, bb.w));
    *(f16x4*)(table + (size_t)q * F + f4) = o;
}

// ---- pass 1: per-chunk LDS histogram over buckets -------------------------
__global__ void __launch_bounds__(512) k_bcount(const int* __restrict__ col,
                                                int* __restrict__ bcnt) {
    __shared__ int cnt[NBKT];
    for (int i = threadIdx.x; i < NBKT; i += 512) cnt[i] = 0;
    __syncthreads();
    int base = blockIdx.x * CHUNK;
    for (int i = threadIdx.x; i < CHUNK; i += 512)
        atomicAdd(&cnt[col[base + i] >> BSHIFT], 1);
    __syncthreads();
    for (int i = threadIdx.x; i < NBKT; i += 512)
        bcnt[i * NCH + blockIdx.x] = cnt[i];      // bucket-major
}

// ---- pass 2a: per-bucket scan of 1024 chunk-counts ------------------------
__global__ void __launch_bounds__(512) k_bscan_local(const int* __restrict__ bcnt,
                                                     int* __restrict__ brel,
                                                     int* __restrict__ btot) {
    __shared__ int sums[512];
    int b = blockIdx.x;
    int t = threadIdx.x;
    int i0 = b * NCH + 2 * t;
    int c0 = bcnt[i0], c1 = bcnt[i0 + 1];
    int s = c0 + c1;
    sums[t] = s;
    __syncthreads();
    for (int off = 1; off < 512; off <<= 1) {
        int v = 0;
        if (t >= off) v = sums[t - off];
        __syncthreads();
        if (t >= off) sums[t] += v;
        __syncthreads();
    }
    int excl = sums[t] - s;
    brel[i0]     = excl;
    brel[i0 + 1] = excl + c0;
    if (t == 511) btot[b] = sums[511];
}

// ---- pass 2b: scan 782 bucket totals (1024 threads); zero gsum/gcnt -------
__global__ void __launch_bounds__(1024) k_bscan_base(const int* __restrict__ btot,
                                                     int* __restrict__ bbase,
                                                     float* __restrict__ gsum,
                                                     float* __restrict__ gcnt) {
    __shared__ int sums[1024];
    int t = threadIdx.x;
    for (int i = t; i < N_GRAPHS * F; i += 1024) gsum[i] = 0.0f;
    if (t < N_GRAPHS) gcnt[t] = 0.0f;
    int v0 = (t < NBKT) ? btot[t] : 0;
    sums[t] = v0;
    __syncthreads();
    for (int off = 1; off < 1024; off <<= 1) {
        int v = 0;
        if (t >= off) v = sums[t - off];
        __syncthreads();
        if (t >= off) sums[t] += v;
        __syncthreads();
    }
    int excl = sums[t] - v0;
    if (t < NBKT) bbase[t] = excl;
    if (t == NBKT - 1) bbase[NBKT] = excl + v0;   // == N_EDGES
}

// ---- pass 3: scatter edges into bucket segments (LDS cursors) -------------
// entry: {cl:7 @52 | src:20 @32 | ew:f32 @0}
__global__ void __launch_bounds__(512) k_bscatter(const int* __restrict__ row,
                                                  const int* __restrict__ col,
                                                  const float* __restrict__ ew,
                                                  const int* __restrict__ brel,
                                                  const int* __restrict__ bbase,
                                                  unsigned long long* __restrict__ ebuf) {
    __shared__ int cur[NBKT];
    int ch = blockIdx.x;
    for (int i = threadIdx.x; i < NBKT; i += 512)
        cur[i] = bbase[i] + brel[i * NCH + ch];
    __syncthreads();
    int base = ch * CHUNK;
    for (int i = threadIdx.x; i < CHUNK; i += 512) {
        int c = col[base + i];
        int r = row[base + i];
        float w = ew[base + i];
        int bk = c >> BSHIFT;
        int p = atomicAdd(&cur[bk], 1);           // LDS atomic
        unsigned int hi = ((unsigned)(c & (BNODES - 1)) << 20) | (unsigned)r;
        ebuf[p] = ((unsigned long long)hi << 32) | (unsigned long long)__float_as_uint(w);
    }
}

// ---- pass 4: per-bucket degree via LDS atomics -> dinv, y=dinv*x ----------
__global__ void __launch_bounds__(512) k_deg(const unsigned long long* __restrict__ ebuf,
                                             const int* __restrict__ bbase,
                                             const float* __restrict__ x,
                                             float* __restrict__ dinv,
                                             float* __restrict__ y) {
    __shared__ float deg[BNODES];
    int b = blockIdx.x, t = threadIdx.x;
    if (t < BNODES) deg[t] = 1.0f;                // self-loop weight
    __syncthreads();
    int e0 = bbase[b], e1 = bbase[b + 1];
    for (int i = e0 + t; i < e1; i += 512) {
        unsigned long long v = ebuf[i];
        atomicAdd(&deg[(int)(v >> 52)], __uint_as_float((unsigned)v));
    }
    __syncthreads();
    if (t < BNODES) {
        int node = (b << BSHIFT) + t;
        if (node < N_NODES) {
            float di = rsqrtf(deg[t]);
            dinv[node] = di;
            y[node] = di * x[node];
        }
    }
}

// ---- pass 5: layer-1 scalar agg via LDS atomics; qd = {qidx:16 | dinv:f16}
__global__ void __launch_bounds__(512) k_s1q(const unsigned long long* __restrict__ ebuf,
                                             const int* __restrict__ bbase,
                                             const float* __restrict__ y,
                                             const float* __restrict__ dinv,
                                             unsigned int* __restrict__ qd) {
    __shared__ float s[BNODES];
    int b = blockIdx.x, t = threadIdx.x;
    if (t < BNODES) s[t] = 0.0f;
    __syncthreads();
    int e0 = bbase[b], e1 = bbase[b + 1];
    for (int i = e0 + t; i < e1; i += 512) {
        unsigned long long v = ebuf[i];
        int src = (int)((v >> 32) & 0xFFFFF);
        atomicAdd(&s[(int)(v >> 52)], __uint_as_float((unsigned)v) * y[src]);  // y: L2
    }
    __syncthreads();
    if (t < BNODES) {
        int node = (b << BSHIFT) + t;
        if (node < N_NODES) {
            float di = dinv[node];
            float s1v = (s[t] + y[node]) * di;
            float q = rintf(fmaf(s1v, QSCALE, 8.0f * QSCALE));
            q = fminf(fmaxf(q, 0.0f), (float)(QLEV - 1));
            f16 dh = (f16)di;
            qd[node] = ((unsigned)q << 16) | (unsigned)(*(unsigned short*)&dh);
        }
    }
}

// ---- pass 6: layer-2 agg: staged batches + feature-parallel LDS accumulate
// acc[cl][f] += (ew*d_src) * table[q_src][f]; lane = feature; no sort needed.
__global__ void __launch_bounds__(512) k_agg(const unsigned long long* __restrict__ ebuf,
                                             const int* __restrict__ bbase,
                                             const f16* __restrict__ table,
                                             const unsigned int* __restrict__ qd,
                                             f16* __restrict__ a1h) {
    __shared__ float acc[BNODES * F];             // 32 KB
    __shared__ unsigned long long stg[512];       // {cl:7 @45 | q:13 @32 | wq:f32}
    int t = threadIdx.x;
    int lane = t & 63;
    int wv   = t >> 6;                            // 8 waves
    for (int i = t; i < BNODES * F; i += 512) acc[i] = 0.0f;
    int b = blockIdx.x;
    int e0 = bbase[b], e1 = bbase[b + 1];
    for (int base = e0; base < e1; base += 512) {
        int cnt = min(512, e1 - base);
        __syncthreads();                          // staging safe to overwrite
        if (t < cnt) {
            unsigned long long v = ebuf[base + t];
            int cl  = (int)(v >> 52);
            int src = (int)((v >> 32) & 0xFFFFF);
            unsigned q = qd[src];                 // 400KB, L2-resident
            float wq = __uint_as_float((unsigned)v) * f16bits_to_f((unsigned short)q);
            stg[t] = ((unsigned long long)cl << 45) | ((unsigned long long)(q >> 16) << 32)
                   | (unsigned long long)__float_as_uint(wq);
        }
        __syncthreads();
        int i0 = wv * 64;
        int i1 = min(i0 + 64, cnt);
        int i = i0;
        for (; i + 3 < i1; i += 4) {              // 4 independent chains in flight
            unsigned long long m0 = stg[i],     m1 = stg[i + 1];
            unsigned long long m2 = stg[i + 2], m3 = stg[i + 3];
            float t0 = (float)table[(int)((m0 >> 32) & 0x1FFF) * F + lane];
            float t1 = (float)table[(int)((m1 >> 32) & 0x1FFF) * F + lane];
            float t2 = (float)table[(int)((m2 >> 32) & 0x1FFF) * F + lane];
            float t3 = (float)table[(int)((m3 >> 32) & 0x1FFF) * F + lane];
            atomicAdd(&acc[(int)(m0 >> 45) * F + lane], __uint_as_float((unsigned)m0) * t0);
            atomicAdd(&acc[(int)(m1 >> 45) * F + lane], __uint_as_float((unsigned)m1) * t1);
            atomicAdd(&acc[(int)(m2 >> 45) * F + lane], __uint_as_float((unsigned)m2) * t2);
            atomicAdd(&acc[(int)(m3 >> 45) * F + lane], __uint_as_float((unsigned)m3) * t3);
        }
        for (; i < i1; i++) {
            unsigned long long m0 = stg[i];
            float t0 = (float)table[(int)((m0 >> 32) & 0x1FFF) * F + lane];
            atomicAdd(&acc[(int)(m0 >> 45) * F + lane], __uint_as_float((unsigned)m0) * t0);
        }
    }
    __syncthreads();
    // epilogue: a1h[node][f] = fp16( d_c*(acc + d_c*table[q_c][f]) )
    for (int idx = t; idx < BNODES * F; idx += 512) {
        int nl = idx >> 6, f = idx & 63;
        int node = (b << BSHIFT) + nl;
        if (node < N_NODES) {
            unsigned qs = qd[node];
            float dc = f16bits_to_f((unsigned short)qs);
            float sf = (float)table[(int)(qs >> 16) * F + f];
            a1h[(size_t)node * F + f] = (f16)(dc * (acc[idx] + dc * sf));
        }
    }
}

// ---- pass 7: fused h2 matmul (+bias+gelu) and mean-pool; W2 in VGPRs ------
#define STRIP 32                                   // nodes per wave
__global__ void __launch_bounds__(256) k_h2pool(const f16* __restrict__ a1h,
                                                const float* __restrict__ W2,
                                                const float* __restrict__ b2,
                                                const int* __restrict__ batch,
                                                float* __restrict__ gsum,
                                                float* __restrict__ gcnt) {
    int lane = threadIdx.x & 63;
    int wv   = threadIdx.x >> 6;
    int gw   = blockIdx.x * 4 + wv;
    int n0 = gw * STRIP;
    if (n0 >= N_NODES) return;
    int n1 = min(n0 + STRIP, N_NODES);
    float w2r[F];                                  // column W2[:,lane] in regs
#pragma unroll
    for (int k = 0; k < F; k++) w2r[k] = W2[k * F + lane];
    float b2f = b2[lane];
    int curg = batch[n0];
    float run = 0.0f;
    int   rl  = 0;
    for (int n = n0; n < n1; n++) {
        int g = batch[n];
        if (g != curg) {
            atomicAdd(&gsum[curg * F + lane], run);
            if (lane == 0) atomicAdd(&gcnt[curg], (float)rl);
            run = 0.0f; rl = 0; curg = g;
        }
        const f16x8* rowp = (const f16x8*)(a1h + (size_t)n * F);
        float acc = b2f;
#pragma unroll
        for (int k8 = 0; k8 < F / 8; k8++) {
            f16x8 r = rowp[k8];                    // uniform 16B -> broadcast
            acc = fmaf((float)r[0], w2r[8 * k8 + 0], acc);
            acc = fmaf((float)r[1], w2r[8 * k8 + 1], acc);
            acc = fmaf((float)r[2], w2r[8 * k8 + 2], acc);
            acc = fmaf((float)r[3], w2r[8 * k8 + 3], acc);
            acc = fmaf((float)r[4], w2r[8 * k8 + 4], acc);
            acc = fmaf((float)r[5], w2r[8 * k8 + 5], acc);
            acc = fmaf((float)r[6], w2r[8 * k8 + 6], acc);
            acc = fmaf((float)r[7], w2r[8 * k8 + 7], acc);
        }
        run += gelu_fast(acc);
        rl++;
    }
    atomicAdd(&gsum[curg * F + lane], run);
    if (lane == 0) atomicAdd(&gcnt[curg], (float)rl);
}

// ---- final MLP: one wave per graph ----------------------------------------
__global__ void __launch_bounds__(256) k_final(const float* __restrict__ gsum,
                                               const float* __restrict__ gcnt,
                                               const float* __restrict__ fc1W,
                                               const float* __restrict__ fc1b,
                                               const float* __restrict__ fc2W,
                                               const float* __restrict__ fc2b,
                                               float* __restrict__ out) {
    __shared__ float sm[4][F];
    int lane = threadIdx.x & 63;
    int wv   = threadIdx.x >> 6;
    int g = blockIdx.x * 4 + wv;
    if (g >= N_GRAPHS) return;
    float c = gcnt[g];
    float m = gsum[g * F + lane] / fmaxf(c, 1.0f);
    sm[wv][lane] = m;
    float o = 0.0f;
    if (lane < 32) {
        float acc = fc1b[lane];
#pragma unroll
        for (int k = 0; k < F; k++) acc = fmaf(sm[wv][k], fc1W[k * 32 + lane], acc);
        o = gelu_f(acc) * fc2W[lane];
    }
    for (int off = 32; off; off >>= 1) o += __shfl_down(o, off);
    if (lane == 0) out[g] = o + fc2b[0];
}

// ---------------------------------------------------------------------------

extern "C" void kernel_launch(void* const* d_in, const int* in_sizes, int n_in,
                              void* d_out, int out_size, void* d_ws, size_t ws_size,
                              hipStream_t stream) {
    const float* x    = (const float*)d_in[0];
    const int*   ei   = (const int*)  d_in[1];   // [2, E]
    const float* ea   = (const float*)d_in[2];
    const int*   bat  = (const int*)  d_in[3];
    const float* W1   = (const float*)d_in[4];
    const float* b1   = (const float*)d_in[5];
    const float* W2   = (const float*)d_in[6];
    const float* b2   = (const float*)d_in[7];
    const float* fc1W = (const float*)d_in[8];
    const float* fc1b = (const float*)d_in[9];
    const float* fc2W = (const float*)d_in[10];
    const float* fc2b = (const float*)d_in[11];
    float* out = (float*)d_out;

    const int* row = ei;
    const int* col = ei + N_EDGES;

    size_t off = 0;
    auto alloc = [&](size_t bytes) -> void* {
        void* p = (char*)d_ws + off;
        off = (off + bytes + 255) & ~(size_t)255;
        return p;
    };
    int*   bcnt  = (int*)alloc((size_t)NBKT * NCH * 4);            // 3.2 MB
    int*   brel  = (int*)alloc((size_t)NBKT * NCH * 4);            // 3.2 MB
    int*   btot  = (int*)alloc((size_t)NBKT * 4);
    int*   bbase = (int*)alloc((size_t)(NBKT + 1) * 4);
    unsigned long long* ebuf = (unsigned long long*)alloc((size_t)N_EDGES * 8); // 25.6 MB
    float* dinv = (float*)alloc((size_t)N_NODES * 4);
    float* yv   = (float*)alloc((size_t)N_NODES * 4);
    unsigned int* qd = (unsigned int*)alloc((size_t)N_NODES * 4);  // 400 KB
    f16*   table = (f16*)alloc((size_t)QLEV * F * 2);              // 1 MB
    f16*   a1h  = (f16*)alloc((size_t)N_NODES * F * 2);            // 12.8 MB (no alias: ebuf live)
    float* gsum = (float*)alloc((size_t)N_GRAPHS * F * 4);
    float* gcnt = (float*)alloc((size_t)N_GRAPHS * 4);
    (void)ws_size; (void)n_in; (void)in_sizes; (void)out_size;

    k_table      <<<(QLEV * 16) / 256, 256, 0, stream>>>(W1, b1, table);
    k_bcount     <<<NCH, 512, 0, stream>>>(col, bcnt);
    k_bscan_local<<<NBKT, 512, 0, stream>>>(bcnt, brel, btot);
    k_bscan_base <<<1, 1024, 0, stream>>>(btot, bbase, gsum, gcnt);
    k_bscatter   <<<NCH, 512, 0, stream>>>(row, col, ea, brel, bbase, ebuf);
    k_deg        <<<NBKT, 512, 0, stream>>>(ebuf, bbase, x, dinv, yv);
    k_s1q        <<<NBKT, 512, 0, stream>>>(ebuf, bbase, yv, dinv, qd);
    k_agg        <<<NBKT, 512, 0, stream>>>(ebuf, bbase, table, qd, a1h);
    {
        int waves = (N_NODES + STRIP - 1) / STRIP;        // 3125
        k_h2pool <<<(waves + 3) / 4, 256, 0, stream>>>(a1h, W2, b2, bat, gsum, gcnt);
    }
    k_final      <<<(N_GRAPHS + 3) / 4, 256, 0, stream>>>(gsum, gcnt, fc1W, fc1b, fc2W, fc2b, out);
}

// Round 14
// 301.756 us; speedup vs baseline: 5.3230x; 5.3230x over previous
//
#include <hip/hip_runtime.h>
#include <math.h>

#define N_NODES  100000
#define N_EDGES  3200000
#define N_GRAPHS 256
#define F        64

// bucketed counting sort params
#define BSHIFT   8
#define BNODES   256                    // nodes per bucket
#define NBKT     391                    // ceil(N_NODES / BNODES)
#define NCH      1024                   // edge chunks
#define CHUNK    3125                   // edges per chunk (NCH*CHUNK == N_EDGES)
#define MAXB     9000                   // LDS-staged edges per bucket (avg 8192, sd ~90)

// s1 quantization: 8192 levels over [-8, 8); step = 1/512
#define QLEV     8192
#define QSCALE   512.0f
#define QINV     (1.0f / 512.0f)

typedef _Float16 f16;
typedef __attribute__((ext_vector_type(4))) _Float16 f16x4;
typedef __attribute__((ext_vector_type(8))) _Float16 f16x8;

__device__ __forceinline__ float gelu_f(float x) {
    float x3 = x * x * x;
    float inner = 0.7978845608028654f * (x + 0.044715f * x3);
    return 0.5f * x * (1.0f + tanhf(inner));
}

// fast gelu: 0.5x(1+tanh(u)) = x*(1-rcp(exp2(2u*log2e)+1)); ~1ulp exp2/rcp
__device__ __forceinline__ float gelu_fast(float x) {
    const float c1 = 2.3022082232f;     // 2*log2(e)*0.7978845608
    const float c2 = 0.1029432407f;     // c1*0.044715
    float x2 = x * x;
    float t  = x * fmaf(c2, x2, c1);
    float E  = __builtin_amdgcn_exp2f(t);
    float r  = __builtin_amdgcn_rcpf(E + 1.0f);
    return fmaf(-x, r, x);
}

__device__ __forceinline__ float f16bits_to_f(unsigned short u) {
    f16 h = *(f16*)&u;
    return (float)h;
}

// ---- gelu lookup table: table[q][f] = fp16(gelu(s_q*W1_f + b1_f)) ---------
__global__ void __launch_bounds__(256) k_table(const float* __restrict__ W1,
                                               const float* __restrict__ b1,
                                               f16* __restrict__ table) {
    int i = blockIdx.x * 256 + threadIdx.x;      // QLEV*16 items
    int q  = i >> 4;
    int f4 = (i & 15) << 2;
    float s = (float)q * QINV - 8.0f;
    const float4 w  = *(const float4*)(W1 + f4);
    const float4 bb = *(const float4*)(b1 + f4);
    f16x4 o;
    o.x = (f16)gelu_fast(fmaf(s, w.x, bb.x));
    o.y = (f16)gelu_fast(fmaf(s, w.y, bb.y));
    o.z = (f16)gelu_fast(fmaf(s, w.z, bb.z));
    o.w = (f16)gelu_fast(fmaf(s, w.w, bb.w));
    *(f16x4*)(table + (size_t)q * F + f4) = o;
}

// ---- pass 1: per-chunk LDS histogram over buckets -------------------------
__global__ void __launch_bounds__(512) k_bcount(const int* __restrict__ col,
                                                int* __restrict__ bcnt) {
    __shared__ int cnt[NBKT];
    for (int i = threadIdx.x; i < NBKT; i += 512) cnt[i] = 0;
    __syncthreads();
    int base = blockIdx.x * CHUNK;
    for (int i = threadIdx.x; i < CHUNK; i += 512)
        atomicAdd(&cnt[col[base + i] >> BSHIFT], 1);
    __syncthreads();
    for (int i = threadIdx.x; i < NBKT; i += 512)
        bcnt[i * NCH + blockIdx.x] = cnt[i];      // bucket-major
}

// ---- pass 2a: per-bucket scan of 1024 chunk-counts ------------------------
__global__ void __launch_bounds__(512) k_bscan_local(const int* __restrict__ bcnt,
                                                     int* __restrict__ brel,
                                                     int* __restrict__ btot) {
    __shared__ int sums[512];
    int b = blockIdx.x;
    int t = threadIdx.x;
    int i0 = b * NCH + 2 * t;
    int c0 = bcnt[i0], c1 = bcnt[i0 + 1];
    int s = c0 + c1;
    sums[t] = s;
    __syncthreads();
    for (int off = 1; off < 512; off <<= 1) {
        int v = 0;
        if (t >= off) v = sums[t - off];
        __syncthreads();
        if (t >= off) sums[t] += v;
        __syncthreads();
    }
    int excl = sums[t] - s;
    brel[i0]     = excl;
    brel[i0 + 1] = excl + c0;
    if (t == 511) btot[b] = sums[511];
}

// ---- pass 2b: scan 391 bucket totals; also zero gsum/gcnt -----------------
__global__ void __launch_bounds__(512) k_bscan_base(const int* __restrict__ btot,
                                                    int* __restrict__ bbase,
                                                    float* __restrict__ gsum,
                                                    float* __restrict__ gcnt) {
    __shared__ int sums[512];
    int t = threadIdx.x;
    for (int i = t; i < N_GRAPHS * F; i += 512) gsum[i] = 0.0f;
    if (t < N_GRAPHS) gcnt[t] = 0.0f;
    int v0 = (t < NBKT) ? btot[t] : 0;
    sums[t] = v0;
    __syncthreads();
    for (int off = 1; off < 512; off <<= 1) {
        int v = 0;
        if (t >= off) v = sums[t - off];
        __syncthreads();
        if (t >= off) sums[t] += v;
        __syncthreads();
    }
    int excl = sums[t] - v0;
    if (t < NBKT) bbase[t] = excl;
    if (t == NBKT - 1) bbase[NBKT] = excl + v0;   // == N_EDGES
}

// ---- pass 3: scatter edges into bucket segments, chunk-sorted for
//      coalesced writes: LDS counting sort of the 3125-edge chunk, then
//      sequential writeout (runs of ~8 consecutive ebuf slots per bucket).
__global__ void __launch_bounds__(512) k_bscatter(const int* __restrict__ row,
                                                  const int* __restrict__ col,
                                                  const float* __restrict__ ew,
                                                  const int* __restrict__ brel,
                                                  const int* __restrict__ bbase,
                                                  unsigned long long* __restrict__ ebuf) {
    __shared__ unsigned long long sbuf[CHUNK];    // 25 KB
    __shared__ unsigned short    sbk[CHUNK];      // 6.25 KB
    __shared__ int hist[NBKT];
    __shared__ int exc[NBKT];
    __shared__ int lcur[NBKT];
    __shared__ int gdst[NBKT];
    __shared__ int sums[512];
    int ch = blockIdx.x;
    int t = threadIdx.x;
    for (int i = t; i < NBKT; i += 512) {
        hist[i] = 0;
        gdst[i] = bbase[i] + brel[i * NCH + ch];
    }
    __syncthreads();
    int base = ch * CHUNK;
    // pass 1: histogram over buckets
    for (int i = t; i < CHUNK; i += 512)
        atomicAdd(&hist[col[base + i] >> BSHIFT], 1);
    __syncthreads();
    // exclusive scan of hist (padded Hillis-Steele over 512)
    int v0 = (t < NBKT) ? hist[t] : 0;
    sums[t] = v0;
    __syncthreads();
    for (int off = 1; off < 512; off <<= 1) {
        int v = 0;
        if (t >= off) v = sums[t - off];
        __syncthreads();
        if (t >= off) sums[t] += v;
        __syncthreads();
    }
    if (t < NBKT) {
        int e = sums[t] - v0;
        exc[t] = e;
        lcur[t] = e;
    }
    __syncthreads();
    // pass 2: scatter into LDS, sorted by bucket (re-read inputs: L2-hot)
    for (int i = t; i < CHUNK; i += 512) {
        int c = col[base + i];
        int r = row[base + i];
        float w = ew[base + i];
        int bk = c >> BSHIFT;
        int p = atomicAdd(&lcur[bk], 1);          // LDS atomic
        unsigned int hi = ((unsigned)(c & (BNODES - 1)) << 20) | (unsigned)r;
        sbuf[p] = ((unsigned long long)hi << 32) | (unsigned long long)__float_as_uint(w);
        sbk[p] = (unsigned short)bk;
    }
    __syncthreads();
    // writeout: consecutive j within a bucket-run -> consecutive ebuf slots
    for (int j = t; j < CHUNK; j += 512) {
        int bk = sbk[j];
        ebuf[gdst[bk] + (j - exc[bk])] = sbuf[j];
    }
}

// ---- pass 4: per-bucket sort + degree; LDS-staged (one HBM read of ebuf) --
__global__ void __launch_bounds__(512) k_bbuild(const unsigned long long* __restrict__ ebuf,
                                                const int* __restrict__ bbase,
                                                const float* __restrict__ x,
                                                unsigned long long* __restrict__ csr,
                                                int* __restrict__ offs,
                                                float* __restrict__ dinv,
                                                float* __restrict__ y) {
    __shared__ unsigned long long st[MAXB];       // 72 KB
    __shared__ int   cnt[BNODES];
    __shared__ float deg[BNODES];
    __shared__ int   cur[BNODES];
    __shared__ int   sc[BNODES];
    int b = blockIdx.x;
    int t = threadIdx.x;
    int e0 = bbase[b], e1 = bbase[b + 1];
    int len = e1 - e0;
    int sl = min(len, MAXB);
    if (t < BNODES) { cnt[t] = 0; deg[t] = 1.0f; }   // 1 = self-loop weight
    for (int i = t; i < sl; i += 512) st[i] = ebuf[e0 + i];
    __syncthreads();
    for (int i = t; i < len; i += 512) {
        unsigned long long v = (i < MAXB) ? st[i] : ebuf[e0 + i];
        int cl = (int)(v >> 52);
        atomicAdd(&cnt[cl], 1);
        atomicAdd(&deg[cl], __uint_as_float((unsigned)v));
    }
    __syncthreads();
    int c = 0;
    if (t < BNODES) { c = cnt[t]; sc[t] = c; }
    __syncthreads();
    for (int off = 1; off < BNODES; off <<= 1) {
        int v = 0;
        if (t >= off && t < BNODES) v = sc[t - off];
        __syncthreads();
        if (t >= off && t < BNODES) sc[t] += v;
        __syncthreads();
    }
    if (t < BNODES) {
        int loff = sc[t] - c;
        cur[t] = loff;
        int node = (b << BSHIFT) + t;
        if (node < N_NODES) {
            offs[node] = e0 + loff;
            float di = rsqrtf(deg[t]);
            dinv[node] = di;
            y[node] = di * x[node];
        }
        if (b == 0 && t == 0) offs[N_NODES] = N_EDGES;
    }
    __syncthreads();
    for (int i = t; i < len; i += 512) {
        unsigned long long v = (i < MAXB) ? st[i] : ebuf[e0 + i];
        int cl = (int)(v >> 52);
        int p = atomicAdd(&cur[cl], 1);       // LDS atomic
        csr[e0 + p] = v;
    }
}

// ---- pass 5: layer-1 scalar agg by CSR walk; qd = {qidx:16 | dinv:f16} ----
__global__ void __launch_bounds__(256) k_s1q(const unsigned long long* __restrict__ csr,
                                             const int* __restrict__ offs,
                                             const float* __restrict__ y,
                                             const float* __restrict__ dinv,
                                             unsigned int* __restrict__ qd) {
    int lane = threadIdx.x & 63;
    int wave = (blockIdx.x * 256 + threadIdx.x) >> 6;
    int node = wave * 4 + (lane >> 4);               // grid exact: 6250 blocks
    int l = lane & 15;
    int e0 = offs[node], e1 = offs[node + 1];
    float s = 0.0f;
    for (int j = e0 + l; j < e1; j += 16) {
        unsigned long long v = csr[j];
        int src = (int)((v >> 32) & 0xFFFFF);
        s = fmaf(__uint_as_float((unsigned)v), y[src], s);   // y: 400KB L2-resident
    }
#pragma unroll
    for (int m = 1; m < 16; m <<= 1) s += __shfl_xor(s, m);  // within 16-lane group
    if (l == 0) {
        float di = dinv[node];
        float s1v = (s + y[node]) * di;
        float q = rintf(fmaf(s1v, QSCALE, 8.0f * QSCALE));
        q = fminf(fmaxf(q, 0.0f), (float)(QLEV - 1));
        f16 dh = (f16)di;
        qd[node] = ((unsigned)q << 16) | (unsigned)(*(unsigned short*)&dh);
    }
}

// ---- pass 6: layer-2 agg from 1MB table; unroll-8 batched loads -----------
// a1h[c,f] = fp16( d_c*( sum_e (ew*d_src)*table[q_src][f] + d_c*table[q_c][f] ) )
__global__ void __launch_bounds__(256) k_agg(const unsigned long long* __restrict__ csr,
                                             const int* __restrict__ offs,
                                             const f16* __restrict__ table,
                                             const unsigned int* __restrict__ qd,
                                             f16* __restrict__ a1h) {
    int lane = threadIdx.x & 63;
    int wave = (blockIdx.x * 256 + threadIdx.x) >> 6;
    int node = wave * 4 + (lane >> 4);               // grid exact: 6250 blocks
    int l4 = (lane & 15) * 4;
    int e0 = offs[node], e1 = offs[node + 1];
    unsigned qs = qd[node];                          // issued early, used in epilogue
    float4 a = make_float4(0.f, 0.f, 0.f, 0.f);
    float4 b = make_float4(0.f, 0.f, 0.f, 0.f);
    int j = e0;
    for (; j + 7 < e1; j += 8) {
        unsigned long long v0 = csr[j],     v1 = csr[j + 1];
        unsigned long long v2 = csr[j + 2], v3 = csr[j + 3];
        unsigned long long v4 = csr[j + 4], v5 = csr[j + 5];
        unsigned long long v6 = csr[j + 6], v7 = csr[j + 7];
        unsigned q0 = qd[(int)((v0 >> 32) & 0xFFFFF)];
        unsigned q1 = qd[(int)((v1 >> 32) & 0xFFFFF)];
        unsigned q2 = qd[(int)((v2 >> 32) & 0xFFFFF)];
        unsigned q3 = qd[(int)((v3 >> 32) & 0xFFFFF)];
        unsigned q4 = qd[(int)((v4 >> 32) & 0xFFFFF)];
        unsigned q5 = qd[(int)((v5 >> 32) & 0xFFFFF)];
        unsigned q6 = qd[(int)((v6 >> 32) & 0xFFFFF)];
        unsigned q7 = qd[(int)((v7 >> 32) & 0xFFFFF)];
        const f16x4 r0 = *(const f16x4*)(table + (size_t)(q0 >> 16) * F + l4);
        const f16x4 r1 = *(const f16x4*)(table + (size_t)(q1 >> 16) * F + l4);
        const f16x4 r2 = *(const f16x4*)(table + (size_t)(q2 >> 16) * F + l4);
        const f16x4 r3 = *(const f16x4*)(table + (size_t)(q3 >> 16) * F + l4);
        const f16x4 r4 = *(const f16x4*)(table + (size_t)(q4 >> 16) * F + l4);
        const f16x4 r5 = *(const f16x4*)(table + (size_t)(q5 >> 16) * F + l4);
        const f16x4 r6 = *(const f16x4*)(table + (size_t)(q6 >> 16) * F + l4);
        const f16x4 r7 = *(const f16x4*)(table + (size_t)(q7 >> 16) * F + l4);
        float w0 = __uint_as_float((unsigned)v0) * f16bits_to_f((unsigned short)q0);
        float w1 = __uint_as_float((unsigned)v1) * f16bits_to_f((unsigned short)q1);
        float w2 = __uint_as_float((unsigned)v2) * f16bits_to_f((unsigned short)q2);
        float w3 = __uint_as_float((unsigned)v3) * f16bits_to_f((unsigned short)q3);
        float w4 = __uint_as_float((unsigned)v4) * f16bits_to_f((unsigned short)q4);
        float w5 = __uint_as_float((unsigned)v5) * f16bits_to_f((unsigned short)q5);
        float w6 = __uint_as_float((unsigned)v6) * f16bits_to_f((unsigned short)q6);
        float w7 = __uint_as_float((unsigned)v7) * f16bits_to_f((unsigned short)q7);
        a.x = fmaf(w0, (float)r0.x, a.x); a.y = fmaf(w0, (float)r0.y, a.y);
        a.z = fmaf(w0, (float)r0.z, a.z); a.w = fmaf(w0, (float)r0.w, a.w);
        b.x = fmaf(w1, (float)r1.x, b.x); b.y = fmaf(w1, (float)r1.y, b.y);
        b.z = fmaf(w1, (float)r1.z, b.z); b.w = fmaf(w1, (float)r1.w, b.w);
        a.x = fmaf(w2, (float)r2.x, a.x); a.y = fmaf(w2, (float)r2.y, a.y);
        a.z = fmaf(w2, (float)r2.z, a.z); a.w = fmaf(w2, (float)r2.w, a.w);
        b.x = fmaf(w3, (float)r3.x, b.x); b.y = fmaf(w3, (float)r3.y, b.y);
        b.z = fmaf(w3, (float)r3.z, b.z); b.w = fmaf(w3, (float)r3.w, b.w);
        a.x = fmaf(w4, (float)r4.x, a.x); a.y = fmaf(w4, (float)r4.y, a.y);
        a.z = fmaf(w4, (float)r4.z, a.z); a.w = fmaf(w4, (float)r4.w, a.w);
        b.x = fmaf(w5, (float)r5.x, b.x); b.y = fmaf(w5, (float)r5.y, b.y);
        b.z = fmaf(w5, (float)r5.z, b.z); b.w = fmaf(w5, (float)r5.w, b.w);
        a.x = fmaf(w6, (float)r6.x, a.x); a.y = fmaf(w6, (float)r6.y, a.y);
        a.z = fmaf(w6, (float)r6.z, a.z); a.w = fmaf(w6, (float)r6.w, a.w);
        b.x = fmaf(w7, (float)r7.x, b.x); b.y = fmaf(w7, (float)r7.y, b.y);
        b.z = fmaf(w7, (float)r7.z, b.z); b.w = fmaf(w7, (float)r7.w, b.w);
    }
    for (; j < e1; j++) {
        unsigned long long v0 = csr[j];
        unsigned q0 = qd[(int)((v0 >> 32) & 0xFFFFF)];
        const f16x4 r0 = *(const f16x4*)(table + (size_t)(q0 >> 16) * F + l4);
        float w0 = __uint_as_float((unsigned)v0) * f16bits_to_f((unsigned short)q0);
        a.x = fmaf(w0, (float)r0.x, a.x); a.y = fmaf(w0, (float)r0.y, a.y);
        a.z = fmaf(w0, (float)r0.z, a.z); a.w = fmaf(w0, (float)r0.w, a.w);
    }
    float dc = f16bits_to_f((unsigned short)qs);
    const f16x4 sf = *(const f16x4*)(table + (size_t)(qs >> 16) * F + l4);
    f16x4 o;
    o.x = (f16)(dc * (a.x + b.x + dc * (float)sf.x));
    o.y = (f16)(dc * (a.y + b.y + dc * (float)sf.y));
    o.z = (f16)(dc * (a.z + b.z + dc * (float)sf.z));
    o.w = (f16)(dc * (a.w + b.w + dc * (float)sf.w));
    *(f16x4*)(a1h + (size_t)node * F + l4) = o;
}

// ---- pass 7: fused h2 matmul (+bias+gelu) and mean-pool; W2 in VGPRs ------
#define STRIP 32                                   // nodes per wave
__global__ void __launch_bounds__(256) k_h2pool(const f16* __restrict__ a1h,
                                                const float* __restrict__ W2,
                                                const float* __restrict__ b2,
                                                const int* __restrict__ batch,
                                                float* __restrict__ gsum,
                                                float* __restrict__ gcnt) {
    int lane = threadIdx.x & 63;
    int wv   = threadIdx.x >> 6;
    int gw   = blockIdx.x * 4 + wv;
    int n0 = gw * STRIP;
    if (n0 >= N_NODES) return;
    int n1 = min(n0 + STRIP, N_NODES);
    float w2r[F];                                  // column W2[:,lane] in regs
#pragma unroll
    for (int k = 0; k < F; k++) w2r[k] = W2[k * F + lane];
    float b2f = b2[lane];
    int curg = batch[n0];
    float run = 0.0f;
    int   rl  = 0;
    for (int n = n0; n < n1; n++) {
        int g = batch[n];
        if (g != curg) {
            atomicAdd(&gsum[curg * F + lane], run);
            if (lane == 0) atomicAdd(&gcnt[curg], (float)rl);
            run = 0.0f; rl = 0; curg = g;
        }
        const f16x8* rowp = (const f16x8*)(a1h + (size_t)n * F);
        float acc = b2f;
#pragma unroll
        for (int k8 = 0; k8 < F / 8; k8++) {
            f16x8 r = rowp[k8];                    // uniform 16B -> broadcast
            acc = fmaf((float)r[0], w2r[8 * k8 + 0], acc);
            acc = fmaf((float)r[1], w2r[8 * k8 + 1], acc);
            acc = fmaf((float)r[2], w2r[8 * k8 + 2], acc);
            acc = fmaf((float)r[3], w2r[8 * k8 + 3], acc);
            acc = fmaf((float)r[4], w2r[8 * k8 + 4], acc);
            acc = fmaf((float)r[5], w2r[8 * k8 + 5], acc);
            acc = fmaf((float)r[6], w2r[8 * k8 + 6], acc);
            acc = fmaf((float)r[7], w2r[8 * k8 + 7], acc);
        }
        run += gelu_fast(acc);
        rl++;
    }
    atomicAdd(&gsum[curg * F + lane], run);
    if (lane == 0) atomicAdd(&gcnt[curg], (float)rl);
}

// ---- final MLP: one wave per graph ----------------------------------------
__global__ void __launch_bounds__(256) k_final(const float* __restrict__ gsum,
                                               const float* __restrict__ gcnt,
                                               const float* __restrict__ fc1W,
                                               const float* __restrict__ fc1b,
                                               const float* __restrict__ fc2W,
                                               const float* __restrict__ fc2b,
                                               float* __restrict__ out) {
    __shared__ float sm[4][F];
    int lane = threadIdx.x & 63;
    int wv   = threadIdx.x >> 6;
    int g = blockIdx.x * 4 + wv;
    if (g >= N_GRAPHS) return;
    float c = gcnt[g];
    float m = gsum[g * F + lane] / fmaxf(c, 1.0f);
    sm[wv][lane] = m;
    float o = 0.0f;
    if (lane < 32) {
        float acc = fc1b[lane];
#pragma unroll
        for (int k = 0; k < F; k++) acc = fmaf(sm[wv][k], fc1W[k * 32 + lane], acc);
        o = gelu_f(acc) * fc2W[lane];
    }
    for (int off = 32; off; off >>= 1) o += __shfl_down(o, off);
    if (lane == 0) out[g] = o + fc2b[0];
}

// ---------------------------------------------------------------------------

extern "C" void kernel_launch(void* const* d_in, const int* in_sizes, int n_in,
                              void* d_out, int out_size, void* d_ws, size_t ws_size,
                              hipStream_t stream) {
    const float* x    = (const float*)d_in[0];
    const int*   ei   = (const int*)  d_in[1];   // [2, E]
    const float* ea   = (const float*)d_in[2];
    const int*   bat  = (const int*)  d_in[3];
    const float* W1   = (const float*)d_in[4];
    const float* b1   = (const float*)d_in[5];
    const float* W2   = (const float*)d_in[6];
    const float* b2   = (const float*)d_in[7];
    const float* fc1W = (const float*)d_in[8];
    const float* fc1b = (const float*)d_in[9];
    const float* fc2W = (const float*)d_in[10];
    const float* fc2b = (const float*)d_in[11];
    float* out = (float*)d_out;

    const int* row = ei;
    const int* col = ei + N_EDGES;

    size_t off = 0;
    auto alloc = [&](size_t bytes) -> void* {
        void* p = (char*)d_ws + off;
        off = (off + bytes + 255) & ~(size_t)255;
        return p;
    };
    int*   bcnt  = (int*)alloc((size_t)NBKT * NCH * 4);            // 1.6 MB
    int*   brel  = (int*)alloc((size_t)NBKT * NCH * 4);            // 1.6 MB
    int*   btot  = (int*)alloc((size_t)NBKT * 4);
    int*   bbase = (int*)alloc((size_t)(NBKT + 1) * 4);
    unsigned long long* ebuf = (unsigned long long*)alloc((size_t)N_EDGES * 8); // 25.6 MB
    unsigned long long* csr  = (unsigned long long*)alloc((size_t)N_EDGES * 8); // 25.6 MB
    int*   offs = (int*)  alloc((size_t)(N_NODES + 1) * 4);
    float* dinv = (float*)alloc((size_t)N_NODES * 4);
    float* yv   = (float*)alloc((size_t)N_NODES * 4);
    unsigned int* qd = (unsigned int*)alloc((size_t)N_NODES * 4);  // 400 KB
    f16*   table = (f16*)alloc((size_t)QLEV * F * 2);              // 1 MB
    f16*   a1h  = (f16*)ebuf;                        // alias: ebuf dead after k_bbuild
    float* gsum = (float*)alloc((size_t)N_GRAPHS * F * 4);
    float* gcnt = (float*)alloc((size_t)N_GRAPHS * 4);
    (void)ws_size; (void)n_in; (void)in_sizes; (void)out_size;

    k_table      <<<(QLEV * 16) / 256, 256, 0, stream>>>(W1, b1, table);
    k_bcount     <<<NCH, 512, 0, stream>>>(col, bcnt);
    k_bscan_local<<<NBKT, 512, 0, stream>>>(bcnt, brel, btot);
    k_bscan_base <<<1, 512, 0, stream>>>(btot, bbase, gsum, gcnt);
    k_bscatter   <<<NCH, 512, 0, stream>>>(row, col, ea, brel, bbase, ebuf);
    k_bbuild     <<<NBKT, 512, 0, stream>>>(ebuf, bbase, x, csr, offs, dinv, yv);
    k_s1q        <<<(N_NODES * 16) / 256, 256, 0, stream>>>(csr, offs, yv, dinv, qd);
    k_agg        <<<(N_NODES * 16) / 256, 256, 0, stream>>>(csr, offs, table, qd, a1h);
    {
        int waves = (N_NODES + STRIP - 1) / STRIP;        // 3125
        k_h2pool <<<(waves + 3) / 4, 256, 0, stream>>>(a1h, W2, b2, bat, gsum, gcnt);
    }
    k_final      <<<(N_GRAPHS + 3) / 4, 256, 0, stream>>>(gsum, gcnt, fc1W, fc1b, fc2W, fc2b, out);
}

// Round 15
// 292.634 us; speedup vs baseline: 5.4889x; 1.0312x over previous
//
#include <hip/hip_runtime.h>
#include <math.h>

#define N_NODES  100000
#define N_EDGES  3200000
#define N_GRAPHS 256
#define F        64

// bucketed counting sort params
#define BSHIFT   8
#define BNODES   256                    // nodes per bucket
#define NBKT     391                    // ceil(N_NODES / BNODES)
#define NCH      1024                   // edge chunks
#define CHUNK    3125                   // edges per chunk (NCH*CHUNK == N_EDGES)
#define MAXB     9000                   // LDS-staged edges per bucket (avg 8192, sd ~90)

// s1 quantization: 8192 levels over [-8, 8); step = 1/512
#define QLEV     8192
#define QSCALE   512.0f
#define QINV     (1.0f / 512.0f)

// LDS table window: rows [QWLO, QWLO+QWN) cached per block in k_agg
#define QWLO     3840
#define QWN      512

// ew quantization (unorm12)
#define EWS      4096.0f
#define EWINV    (1.0f / 4096.0f)

typedef _Float16 f16;
typedef __attribute__((ext_vector_type(4))) _Float16 f16x4;
typedef __attribute__((ext_vector_type(8))) _Float16 f16x8;

__device__ __forceinline__ float gelu_f(float x) {
    float x3 = x * x * x;
    float inner = 0.7978845608028654f * (x + 0.044715f * x3);
    return 0.5f * x * (1.0f + tanhf(inner));
}

// fast gelu: 0.5x(1+tanh(u)) = x*(1-rcp(exp2(2u*log2e)+1)); ~1ulp exp2/rcp
__device__ __forceinline__ float gelu_fast(float x) {
    const float c1 = 2.3022082232f;     // 2*log2(e)*0.7978845608
    const float c2 = 0.1029432407f;     // c1*0.044715
    float x2 = x * x;
    float t  = x * fmaf(c2, x2, c1);
    float E  = __builtin_amdgcn_exp2f(t);
    float r  = __builtin_amdgcn_rcpf(E + 1.0f);
    return fmaf(-x, r, x);
}

__device__ __forceinline__ float f16bits_to_f(unsigned short u) {
    f16 h = *(f16*)&u;
    return (float)h;
}

// ---- gelu lookup table: table[q][f] = fp16(gelu(s_q*W1_f + b1_f)) ---------
__global__ void __launch_bounds__(256) k_table(const float* __restrict__ W1,
                                               const float* __restrict__ b1,
                                               f16* __restrict__ table) {
    int i = blockIdx.x * 256 + threadIdx.x;      // QLEV*16 items
    int q  = i >> 4;
    int f4 = (i & 15) << 2;
    float s = (float)q * QINV - 8.0f;
    const float4 w  = *(const float4*)(W1 + f4);
    const float4 bb = *(const float4*)(b1 + f4);
    f16x4 o;
    o.x = (f16)gelu_fast(fmaf(s, w.x, bb.x));
    o.y = (f16)gelu_fast(fmaf(s, w.y, bb.y));
    o.z = (f16)gelu_fast(fmaf(s, w.z, bb.z));
    o.w = (f16)gelu_fast(fmaf(s, w.w, bb.w));
    *(f16x4*)(table + (size_t)q * F + f4) = o;
}

// ---- pass 1: per-chunk LDS histogram over buckets -------------------------
__global__ void __launch_bounds__(512) k_bcount(const int* __restrict__ col,
                                                int* __restrict__ bcnt) {
    __shared__ int cnt[NBKT];
    for (int i = threadIdx.x; i < NBKT; i += 512) cnt[i] = 0;
    __syncthreads();
    int base = blockIdx.x * CHUNK;
    for (int i = threadIdx.x; i < CHUNK; i += 512)
        atomicAdd(&cnt[col[base + i] >> BSHIFT], 1);
    __syncthreads();
    for (int i = threadIdx.x; i < NBKT; i += 512)
        bcnt[i * NCH + blockIdx.x] = cnt[i];      // bucket-major
}

// ---- pass 2a: per-bucket scan of 1024 chunk-counts ------------------------
__global__ void __launch_bounds__(512) k_bscan_local(const int* __restrict__ bcnt,
                                                     int* __restrict__ brel,
                                                     int* __restrict__ btot) {
    __shared__ int sums[512];
    int b = blockIdx.x;
    int t = threadIdx.x;
    int i0 = b * NCH + 2 * t;
    int c0 = bcnt[i0], c1 = bcnt[i0 + 1];
    int s = c0 + c1;
    sums[t] = s;
    __syncthreads();
    for (int off = 1; off < 512; off <<= 1) {
        int v = 0;
        if (t >= off) v = sums[t - off];
        __syncthreads();
        if (t >= off) sums[t] += v;
        __syncthreads();
    }
    int excl = sums[t] - s;
    brel[i0]     = excl;
    brel[i0 + 1] = excl + c0;
    if (t == 511) btot[b] = sums[511];
}

// ---- pass 2b: scan 391 bucket totals; also zero gsum/gcnt -----------------
__global__ void __launch_bounds__(512) k_bscan_base(const int* __restrict__ btot,
                                                    int* __restrict__ bbase,
                                                    float* __restrict__ gsum,
                                                    float* __restrict__ gcnt) {
    __shared__ int sums[512];
    int t = threadIdx.x;
    for (int i = t; i < N_GRAPHS * F; i += 512) gsum[i] = 0.0f;
    if (t < N_GRAPHS) gcnt[t] = 0.0f;
    int v0 = (t < NBKT) ? btot[t] : 0;
    sums[t] = v0;
    __syncthreads();
    for (int off = 1; off < 512; off <<= 1) {
        int v = 0;
        if (t >= off) v = sums[t - off];
        __syncthreads();
        if (t >= off) sums[t] += v;
        __syncthreads();
    }
    int excl = sums[t] - v0;
    if (t < NBKT) bbase[t] = excl;
    if (t == NBKT - 1) bbase[NBKT] = excl + v0;   // == N_EDGES
}

// ---- pass 3: scatter edges into bucket segments, chunk-sorted writes ------
__global__ void __launch_bounds__(512) k_bscatter(const int* __restrict__ row,
                                                  const int* __restrict__ col,
                                                  const float* __restrict__ ew,
                                                  const int* __restrict__ brel,
                                                  const int* __restrict__ bbase,
                                                  unsigned long long* __restrict__ ebuf) {
    __shared__ unsigned long long sbuf[CHUNK];    // 25 KB
    __shared__ unsigned short    sbk[CHUNK];      // 6.25 KB
    __shared__ int hist[NBKT];
    __shared__ int exc[NBKT];
    __shared__ int lcur[NBKT];
    __shared__ int gdst[NBKT];
    __shared__ int sums[512];
    int ch = blockIdx.x;
    int t = threadIdx.x;
    for (int i = t; i < NBKT; i += 512) {
        hist[i] = 0;
        gdst[i] = bbase[i] + brel[i * NCH + ch];
    }
    __syncthreads();
    int base = ch * CHUNK;
    for (int i = t; i < CHUNK; i += 512)
        atomicAdd(&hist[col[base + i] >> BSHIFT], 1);
    __syncthreads();
    int v0 = (t < NBKT) ? hist[t] : 0;
    sums[t] = v0;
    __syncthreads();
    for (int off = 1; off < 512; off <<= 1) {
        int v = 0;
        if (t >= off) v = sums[t - off];
        __syncthreads();
        if (t >= off) sums[t] += v;
        __syncthreads();
    }
    if (t < NBKT) {
        int e = sums[t] - v0;
        exc[t] = e;
        lcur[t] = e;
    }
    __syncthreads();
    for (int i = t; i < CHUNK; i += 512) {
        int c = col[base + i];
        int r = row[base + i];
        float w = ew[base + i];
        int bk = c >> BSHIFT;
        int p = atomicAdd(&lcur[bk], 1);          // LDS atomic
        unsigned int hi = ((unsigned)(c & (BNODES - 1)) << 20) | (unsigned)r;
        sbuf[p] = ((unsigned long long)hi << 32) | (unsigned long long)__float_as_uint(w);
        sbk[p] = (unsigned short)bk;
    }
    __syncthreads();
    for (int j = t; j < CHUNK; j += 512) {
        int bk = sbk[j];
        ebuf[gdst[bk] + (j - exc[bk])] = sbuf[j];
    }
}

// ---- pass 4: per-bucket sort + degree; writes 4B csr {ew:unorm12|src:20} --
__global__ void __launch_bounds__(512) k_bbuild(const unsigned long long* __restrict__ ebuf,
                                                const int* __restrict__ bbase,
                                                const float* __restrict__ x,
                                                unsigned int* __restrict__ csr4,
                                                int* __restrict__ offs,
                                                float* __restrict__ dinv,
                                                float* __restrict__ y) {
    __shared__ unsigned long long st[MAXB];       // 72 KB
    __shared__ int   cnt[BNODES];
    __shared__ float deg[BNODES];
    __shared__ int   cur[BNODES];
    __shared__ int   sc[BNODES];
    int b = blockIdx.x;
    int t = threadIdx.x;
    int e0 = bbase[b], e1 = bbase[b + 1];
    int len = e1 - e0;
    int sl = min(len, MAXB);
    if (t < BNODES) { cnt[t] = 0; deg[t] = 1.0f; }   // 1 = self-loop weight
    for (int i = t; i < sl; i += 512) st[i] = ebuf[e0 + i];
    __syncthreads();
    for (int i = t; i < len; i += 512) {
        unsigned long long v = (i < MAXB) ? st[i] : ebuf[e0 + i];
        int cl = (int)(v >> 52);
        atomicAdd(&cnt[cl], 1);
        atomicAdd(&deg[cl], __uint_as_float((unsigned)v));   // exact ew
    }
    __syncthreads();
    int c = 0;
    if (t < BNODES) { c = cnt[t]; sc[t] = c; }
    __syncthreads();
    for (int off = 1; off < BNODES; off <<= 1) {
        int v = 0;
        if (t >= off && t < BNODES) v = sc[t - off];
        __syncthreads();
        if (t >= off && t < BNODES) sc[t] += v;
        __syncthreads();
    }
    if (t < BNODES) {
        int loff = sc[t] - c;
        cur[t] = loff;
        int node = (b << BSHIFT) + t;
        if (node < N_NODES) {
            offs[node] = e0 + loff;
            float di = rsqrtf(deg[t]);
            dinv[node] = di;
            y[node] = di * x[node];
        }
        if (b == 0 && t == 0) offs[N_NODES] = N_EDGES;
    }
    __syncthreads();
    for (int i = t; i < len; i += 512) {
        unsigned long long v = (i < MAXB) ? st[i] : ebuf[e0 + i];
        int cl = (int)(v >> 52);
        int p = atomicAdd(&cur[cl], 1);       // LDS atomic
        unsigned int ewq = (unsigned int)fminf(__uint_as_float((unsigned)v) * EWS + 0.5f, 4095.0f);
        csr4[e0 + p] = ((unsigned)((v >> 32) & 0xFFFFF)) | (ewq << 20);
    }
}

// ---- pass 5: layer-1 scalar agg by CSR walk; qd = {qidx:16 | dinv:f16} ----
__global__ void __launch_bounds__(256) k_s1q(const unsigned int* __restrict__ csr4,
                                             const int* __restrict__ offs,
                                             const float* __restrict__ y,
                                             const float* __restrict__ dinv,
                                             unsigned int* __restrict__ qd) {
    int lane = threadIdx.x & 63;
    int wave = (blockIdx.x * 256 + threadIdx.x) >> 6;
    int node = wave * 4 + (lane >> 4);               // grid exact: 6250 blocks
    int l = lane & 15;
    int e0 = offs[node], e1 = offs[node + 1];
    float s = 0.0f;
    for (int j = e0 + l; j < e1; j += 16) {
        unsigned int v = csr4[j];
        int src = (int)(v & 0xFFFFF);
        s = fmaf((float)(v >> 20) * EWINV, y[src], s);   // y: 400KB L2-resident
    }
#pragma unroll
    for (int m = 1; m < 16; m <<= 1) s += __shfl_xor(s, m);  // within 16-lane group
    if (l == 0) {
        float di = dinv[node];
        float s1v = (s + y[node]) * di;
        float q = rintf(fmaf(s1v, QSCALE, 8.0f * QSCALE));
        q = fminf(fmaxf(q, 0.0f), (float)(QLEV - 1));
        f16 dh = (f16)di;
        qd[node] = ((unsigned)q << 16) | (unsigned)(*(unsigned short*)&dh);
    }
}

// ---- pass 6: layer-2 agg; LDS table window + global fallback --------------
// a1h[c,f] = fp16( d_c*( sum_e (ew*d_src)*table[q_src][f] + d_c*table[q_c][f] ) )
__global__ void __launch_bounds__(1024) k_agg(const unsigned int* __restrict__ csr4,
                                              const int* __restrict__ offs,
                                              const f16* __restrict__ table,
                                              const unsigned int* __restrict__ qd,
                                              f16* __restrict__ a1h) {
    __shared__ f16 ltab[QWN * F];                 // 64 KB window [QWLO, QWLO+QWN)
    int t = threadIdx.x;
    for (int i = t; i < QWN * F / 4; i += 1024)
        ((f16x4*)ltab)[i] = ((const f16x4*)(table + (size_t)QWLO * F))[i];
    __syncthreads();
    int lane = t & 63;
    int grp  = lane >> 4;
    int l4   = (lane & 15) * 4;
    int wave_g = blockIdx.x * 16 + (t >> 6);      // 16384 waves total
    for (int node = wave_g * 4 + grp; node < N_NODES; node += 16384 * 4) {
        int e0 = offs[node], e1 = offs[node + 1];
        unsigned qs = qd[node];
        float4 a = make_float4(0.f, 0.f, 0.f, 0.f);
        float4 b = make_float4(0.f, 0.f, 0.f, 0.f);
        int j = e0;
        for (; j + 3 < e1; j += 4) {
            unsigned v0 = csr4[j],     v1 = csr4[j + 1];
            unsigned v2 = csr4[j + 2], v3 = csr4[j + 3];
            unsigned d0 = qd[v0 & 0xFFFFF];
            unsigned d1 = qd[v1 & 0xFFFFF];
            unsigned d2 = qd[v2 & 0xFFFFF];
            unsigned d3 = qd[v3 & 0xFFFFF];
            int q0 = d0 >> 16, q1 = d1 >> 16, q2 = d2 >> 16, q3 = d3 >> 16;
            float w0 = (float)(v0 >> 20) * EWINV * f16bits_to_f((unsigned short)d0);
            float w1 = (float)(v1 >> 20) * EWINV * f16bits_to_f((unsigned short)d1);
            float w2 = (float)(v2 >> 20) * EWINV * f16bits_to_f((unsigned short)d2);
            float w3 = (float)(v3 >> 20) * EWINV * f16bits_to_f((unsigned short)d3);
            int inw = ((unsigned)(q0 - QWLO) < QWN) & ((unsigned)(q1 - QWLO) < QWN) &
                      ((unsigned)(q2 - QWLO) < QWN) & ((unsigned)(q3 - QWLO) < QWN);
            f16x4 r0, r1, r2, r3;
            if (__all(inw)) {                     // wave-uniform branch
                r0 = *(const f16x4*)(ltab + (q0 - QWLO) * F + l4);
                r1 = *(const f16x4*)(ltab + (q1 - QWLO) * F + l4);
                r2 = *(const f16x4*)(ltab + (q2 - QWLO) * F + l4);
                r3 = *(const f16x4*)(ltab + (q3 - QWLO) * F + l4);
            } else {
                r0 = *(const f16x4*)(table + (size_t)q0 * F + l4);
                r1 = *(const f16x4*)(table + (size_t)q1 * F + l4);
                r2 = *(const f16x4*)(table + (size_t)q2 * F + l4);
                r3 = *(const f16x4*)(table + (size_t)q3 * F + l4);
            }
            a.x = fmaf(w0, (float)r0.x, a.x); a.y = fmaf(w0, (float)r0.y, a.y);
            a.z = fmaf(w0, (float)r0.z, a.z); a.w = fmaf(w0, (float)r0.w, a.w);
            b.x = fmaf(w1, (float)r1.x, b.x); b.y = fmaf(w1, (float)r1.y, b.y);
            b.z = fmaf(w1, (float)r1.z, b.z); b.w = fmaf(w1, (float)r1.w, b.w);
            a.x = fmaf(w2, (float)r2.x, a.x); a.y = fmaf(w2, (float)r2.y, a.y);
            a.z = fmaf(w2, (float)r2.z, a.z); a.w = fmaf(w2, (float)r2.w, a.w);
            b.x = fmaf(w3, (float)r3.x, b.x); b.y = fmaf(w3, (float)r3.y, b.y);
            b.z = fmaf(w3, (float)r3.z, b.z); b.w = fmaf(w3, (float)r3.w, b.w);
        }
        for (; j < e1; j++) {
            unsigned v0 = csr4[j];
            unsigned d0 = qd[v0 & 0xFFFFF];
            int q0 = d0 >> 16;
            float w0 = (float)(v0 >> 20) * EWINV * f16bits_to_f((unsigned short)d0);
            f16x4 r0;
            if (__all((unsigned)(q0 - QWLO) < QWN))
                r0 = *(const f16x4*)(ltab + (q0 - QWLO) * F + l4);
            else
                r0 = *(const f16x4*)(table + (size_t)q0 * F + l4);
            a.x = fmaf(w0, (float)r0.x, a.x); a.y = fmaf(w0, (float)r0.y, a.y);
            a.z = fmaf(w0, (float)r0.z, a.z); a.w = fmaf(w0, (float)r0.w, a.w);
        }
        float dc = f16bits_to_f((unsigned short)qs);
        const f16x4 sf = *(const f16x4*)(table + (size_t)(qs >> 16) * F + l4);
        f16x4 o;
        o.x = (f16)(dc * (a.x + b.x + dc * (float)sf.x));
        o.y = (f16)(dc * (a.y + b.y + dc * (float)sf.y));
        o.z = (f16)(dc * (a.z + b.z + dc * (float)sf.z));
        o.w = (f16)(dc * (a.w + b.w + dc * (float)sf.w));
        *(f16x4*)(a1h + (size_t)node * F + l4) = o;
    }
}

// ---- pass 7: fused h2 matmul (+bias+gelu) and mean-pool; W2 in VGPRs ------
#define STRIP 32                                   // nodes per wave
__global__ void __launch_bounds__(256) k_h2pool(const f16* __restrict__ a1h,
                                                const float* __restrict__ W2,
                                                const float* __restrict__ b2,
                                                const int* __restrict__ batch,
                                                float* __restrict__ gsum,
                                                float* __restrict__ gcnt) {
    int lane = threadIdx.x & 63;
    int wv   = threadIdx.x >> 6;
    int gw   = blockIdx.x * 4 + wv;
    int n0 = gw * STRIP;
    if (n0 >= N_NODES) return;
    int n1 = min(n0 + STRIP, N_NODES);
    float w2r[F];                                  // column W2[:,lane] in regs
#pragma unroll
    for (int k = 0; k < F; k++) w2r[k] = W2[k * F + lane];
    float b2f = b2[lane];
    int curg = batch[n0];
    float run = 0.0f;
    int   rl  = 0;
    for (int n = n0; n < n1; n++) {
        int g = batch[n];
        if (g != curg) {
            atomicAdd(&gsum[curg * F + lane], run);
            if (lane == 0) atomicAdd(&gcnt[curg], (float)rl);
            run = 0.0f; rl = 0; curg = g;
        }
        const f16x8* rowp = (const f16x8*)(a1h + (size_t)n * F);
        float acc = b2f;
#pragma unroll
        for (int k8 = 0; k8 < F / 8; k8++) {
            f16x8 r = rowp[k8];                    // uniform 16B -> broadcast
            acc = fmaf((float)r[0], w2r[8 * k8 + 0], acc);
            acc = fmaf((float)r[1], w2r[8 * k8 + 1], acc);
            acc = fmaf((float)r[2], w2r[8 * k8 + 2], acc);
            acc = fmaf((float)r[3], w2r[8 * k8 + 3], acc);
            acc = fmaf((float)r[4], w2r[8 * k8 + 4], acc);
            acc = fmaf((float)r[5], w2r[8 * k8 + 5], acc);
            acc = fmaf((float)r[6], w2r[8 * k8 + 6], acc);
            acc = fmaf((float)r[7], w2r[8 * k8 + 7], acc);
        }
        run += gelu_fast(acc);
        rl++;
    }
    atomicAdd(&gsum[curg * F + lane], run);
    if (lane == 0) atomicAdd(&gcnt[curg], (float)rl);
}

// ---- final MLP: one wave per graph ----------------------------------------
__global__ void __launch_bounds__(256) k_final(const float* __restrict__ gsum,
                                               const float* __restrict__ gcnt,
                                               const float* __restrict__ fc1W,
                                               const float* __restrict__ fc1b,
                                               const float* __restrict__ fc2W,
                                               const float* __restrict__ fc2b,
                                               float* __restrict__ out) {
    __shared__ float sm[4][F];
    int lane = threadIdx.x & 63;
    int wv   = threadIdx.x >> 6;
    int g = blockIdx.x * 4 + wv;
    if (g >= N_GRAPHS) return;
    float c = gcnt[g];
    float m = gsum[g * F + lane] / fmaxf(c, 1.0f);
    sm[wv][lane] = m;
    float o = 0.0f;
    if (lane < 32) {
        float acc = fc1b[lane];
#pragma unroll
        for (int k = 0; k < F; k++) acc = fmaf(sm[wv][k], fc1W[k * 32 + lane], acc);
        o = gelu_f(acc) * fc2W[lane];
    }
    for (int off = 32; off; off >>= 1) o += __shfl_down(o, off);
    if (lane == 0) out[g] = o + fc2b[0];
}

// ---------------------------------------------------------------------------

extern "C" void kernel_launch(void* const* d_in, const int* in_sizes, int n_in,
                              void* d_out, int out_size, void* d_ws, size_t ws_size,
                              hipStream_t stream) {
    const float* x    = (const float*)d_in[0];
    const int*   ei   = (const int*)  d_in[1];   // [2, E]
    const float* ea   = (const float*)d_in[2];
    const int*   bat  = (const int*)  d_in[3];
    const float* W1   = (const float*)d_in[4];
    const float* b1   = (const float*)d_in[5];
    const float* W2   = (const float*)d_in[6];
    const float* b2   = (const float*)d_in[7];
    const float* fc1W = (const float*)d_in[8];
    const float* fc1b = (const float*)d_in[9];
    const float* fc2W = (const float*)d_in[10];
    const float* fc2b = (const float*)d_in[11];
    float* out = (float*)d_out;

    const int* row = ei;
    const int* col = ei + N_EDGES;

    size_t off = 0;
    auto alloc = [&](size_t bytes) -> void* {
        void* p = (char*)d_ws + off;
        off = (off + bytes + 255) & ~(size_t)255;
        return p;
    };
    int*   bcnt  = (int*)alloc((size_t)NBKT * NCH * 4);            // 1.6 MB
    int*   brel  = (int*)alloc((size_t)NBKT * NCH * 4);            // 1.6 MB
    int*   btot  = (int*)alloc((size_t)NBKT * 4);
    int*   bbase = (int*)alloc((size_t)(NBKT + 1) * 4);
    unsigned long long* ebuf = (unsigned long long*)alloc((size_t)N_EDGES * 8); // 25.6 MB
    unsigned int* csr4 = (unsigned int*)alloc((size_t)N_EDGES * 4);             // 12.8 MB
    int*   offs = (int*)  alloc((size_t)(N_NODES + 1) * 4);
    float* dinv = (float*)alloc((size_t)N_NODES * 4);
    float* yv   = (float*)alloc((size_t)N_NODES * 4);
    unsigned int* qd = (unsigned int*)alloc((size_t)N_NODES * 4);  // 400 KB
    f16*   table = (f16*)alloc((size_t)QLEV * F * 2);              // 1 MB
    f16*   a1h  = (f16*)ebuf;                        // alias: ebuf dead after k_bbuild
    float* gsum = (float*)alloc((size_t)N_GRAPHS * F * 4);
    float* gcnt = (float*)alloc((size_t)N_GRAPHS * 4);
    (void)ws_size; (void)n_in; (void)in_sizes; (void)out_size;

    k_table      <<<(QLEV * 16) / 256, 256, 0, stream>>>(W1, b1, table);
    k_bcount     <<<NCH, 512, 0, stream>>>(col, bcnt);
    k_bscan_local<<<NBKT, 512, 0, stream>>>(bcnt, brel, btot);
    k_bscan_base <<<1, 512, 0, stream>>>(btot, bbase, gsum, gcnt);
    k_bscatter   <<<NCH, 512, 0, stream>>>(row, col, ea, brel, bbase, ebuf);
    k_bbuild     <<<NBKT, 512, 0, stream>>>(ebuf, bbase, x, csr4, offs, dinv, yv);
    k_s1q        <<<(N_NODES * 16) / 256, 256, 0, stream>>>(csr4, offs, yv, dinv, qd);
    k_agg        <<<1024, 1024, 0, stream>>>(csr4, offs, table, qd, a1h);
    {
        int waves = (N_NODES + STRIP - 1) / STRIP;        // 3125
        k_h2pool <<<(waves + 3) / 4, 256, 0, stream>>>(a1h, W2, b2, bat, gsum, gcnt);
    }
    k_final      <<<(N_GRAPHS + 3) / 4, 256, 0, stream>>>(gsum, gcnt, fc1W, fc1b, fc2W, fc2b, out);
}